// Round 2
// baseline (438.175 us; speedup 1.0000x reference)
//
#include <hip/hip_runtime.h>
#include <stdint.h>

#define NN     6258
#define IMG_N  1600
#define CNN_N  4608
#define OUT_N  50
#define BATCH  64
#define G0SZ   1650
#define G1SZ   4608
#define IMGW   40
#define NPATCH 12

// ---------------- threefry2x32-20, exactly as jax/_src/prng.py ----------------
__host__ __device__ inline void tf2x32(uint32_t k0, uint32_t k1,
                                       uint32_t x0, uint32_t x1,
                                       uint32_t& o0, uint32_t& o1) {
    uint32_t ks[3] = {k0, k1, k0 ^ k1 ^ 0x1BD11BDAu};
    const int rotA[4] = {13, 15, 26, 6};
    const int rotB[4] = {17, 29, 16, 24};
    x0 += ks[0];
    x1 += ks[1];
#pragma unroll
    for (int i = 0; i < 5; ++i) {
        const int* rot = (i & 1) ? rotB : rotA;
#pragma unroll
        for (int j = 0; j < 4; ++j) {
            x0 += x1;
            x1 = (x1 << rot[j]) | (x1 >> (32 - rot[j]));
            x1 ^= x0;
        }
        x0 += ks[(i + 1) % 3];
        x1 += ks[(i + 2) % 3] + (uint32_t)(i + 1);
    }
    o0 = x0;
    o1 = x1;
}

// jax.random.uniform(...)*2-1, PARTITIONABLE mode (jax_threefry_partitionable=True):
// bits[j] = xor-fold of threefry(key, (0, j)) for flat index j < 2^32.
__device__ inline float jax_uniform_pm1(uint32_t k0, uint32_t k1, uint32_t j) {
    uint32_t o0, o1;
    tf2x32(k0, k1, 0u, j, o0, o1);
    uint32_t bits = o0 ^ o1;
    float f = __uint_as_float((bits >> 9) | 0x3f800000u); // [1,2)
    return (f - 1.0f) * 2.0f - 1.0f;                      // [-1,1)
}

// XLA's f32 tanh rational approximation (elemental_ir_emitter EmitTanh),
// with explicit non-contracted f32 ops to match XLA's unfused mul/add.
__device__ inline float tanh_xla_f32(float x) {
    if (fabsf(x) < 0.0004f) return x;
    float xc = fminf(fmaxf(x, -9.0f), 9.0f);
    float x2 = __fmul_rn(xc, xc);
    float num = -2.76076847742355e-16f;
    num = __fadd_rn(__fmul_rn(num, x2), 2.00018790482477e-13f);
    num = __fadd_rn(__fmul_rn(num, x2), -8.60467152213735e-11f);
    num = __fadd_rn(__fmul_rn(num, x2), 5.12229709037114e-08f);
    num = __fadd_rn(__fmul_rn(num, x2), 1.48572235717979e-05f);
    num = __fadd_rn(__fmul_rn(num, x2), 6.37261928875436e-04f);
    num = __fadd_rn(__fmul_rn(num, x2), 4.89352455891786e-03f);
    num = __fmul_rn(num, xc);
    float den = 1.19825839466702e-06f;
    den = __fadd_rn(__fmul_rn(den, x2), 1.18534705686654e-04f);
    den = __fadd_rn(__fmul_rn(den, x2), 2.26843463243900e-03f);
    den = __fadd_rn(__fmul_rn(den, x2), 4.89352518554385e-03f);
    return __fdiv_rn(num, den);
}

__device__ inline float gibbs_decide(double acc, float h, float u) {
    float I32 = (float)(acc + (double)h);   // ref rounds I to f32
    float t = tanh_xla_f32(I32);
    float d = __fadd_rn(t, -u);             // f32 subtract, then sign (sign(0)=0)
    return (d > 0.0f) ? 1.0f : ((d < 0.0f) ? -1.0f : 0.0f);
}

// ---------------- group0: img nodes (0..1599) + out nodes (6208..6257) ----------------
__global__ __launch_bounds__(256) void g0_kernel(float* __restrict__ m,
                                                 const float* __restrict__ J,
                                                 const float* __restrict__ H,
                                                 uint32_t k0, uint32_t k1) {
    int blk = blockIdx.x;
    if (blk < 400) {
        int tid = blk * 256 + (int)threadIdx.x;  // [0, 102400)
        int g = tid >> 6;                        // pixel 0..1599
        int b = tid & 63;
        int r = g / IMGW, c = g % IMGW;
        int pr_lo = (r >= 4) ? (r - 2) / 3 : 0;
        int pr_hi = r / 3; if (pr_hi > NPATCH - 1) pr_hi = NPATCH - 1;
        int pc_lo = (c >= 4) ? (c - 2) / 3 : 0;
        int pc_hi = c / 3; if (pc_hi > NPATCH - 1) pc_hi = NPATCH - 1;
        const float* Jrow = J + (size_t)g * NN;
        const float* mrow = m + (size_t)b * NN;
        double acc = 0.0;
        for (int pr = pr_lo; pr <= pr_hi; ++pr) {
            for (int pc = pc_lo; pc <= pc_hi; ++pc) {
                int base = IMG_N + pr * NPATCH + pc;  // cnn col for f=0
#pragma unroll
                for (int f = 0; f < 32; ++f) {
                    int col = base + f * 144;
                    acc += (double)Jrow[col] * (double)mrow[col];
                }
            }
        }
        float u = jax_uniform_pm1(k0, k1, (uint32_t)(b * G0SZ + g));
        m[(size_t)b * NN + g] = gibbs_decide(acc, H[g], u);
    } else {
        int w = (blk - 400) * 4 + ((int)threadIdx.x >> 6);  // [0, 3200)
        int lane = (int)threadIdx.x & 63;
        int o = w >> 6;   // 0..49
        int b = w & 63;
        const float* Jrow = J + (size_t)(IMG_N + CNN_N + o) * NN + IMG_N;
        const float* mrow = m + (size_t)b * NN + IMG_N;
        double acc = 0.0;
        for (int k = lane; k < CNN_N; k += 64)
            acc += (double)Jrow[k] * (double)mrow[k];
        for (int off = 32; off >= 1; off >>= 1)
            acc += __shfl_xor(acc, off, 64);
        if (lane == 0) {
            float u = jax_uniform_pm1(k0, k1, (uint32_t)(b * G0SZ + IMG_N + o));
            m[(size_t)b * NN + IMG_N + CNN_N + o] =
                gibbs_decide(acc, H[IMG_N + CNN_N + o], u);
        }
    }
}

// ---------------- group1: cnn nodes (1600..6207), thread = c*64+b ----------------
__global__ __launch_bounds__(256) void g1_kernel(float* __restrict__ m,
                                                 const float* __restrict__ J,
                                                 const float* __restrict__ H,
                                                 uint32_t k0, uint32_t k1) {
    int tid = blockIdx.x * 256 + (int)threadIdx.x;  // [0, 294912)
    int cnode = tid >> 6;  // 0..4607
    int b = tid & 63;
    int p = cnode % 144;
    int pr = p / NPATCH, pc = p % NPATCH;
    int r0 = pr * 3, c0 = pc * 3;
    const float* Jrow = J + (size_t)(IMG_N + cnode) * NN;
    const float* mrow = m + (size_t)b * NN;
    double acc = 0.0;
#pragma unroll
    for (int a = 0; a < 5; ++a) {
        int rowbase = (r0 + a) * IMGW + c0;
#pragma unroll
        for (int bb = 0; bb < 5; ++bb) {
            int pix = rowbase + bb;
            acc += (double)Jrow[pix] * (double)mrow[pix];
        }
    }
    const float* Jo = Jrow + IMG_N + CNN_N;
    const float* mo = mrow + IMG_N + CNN_N;
    for (int o = 0; o < OUT_N; ++o)
        acc += (double)Jo[o] * (double)mo[o];
    float u = jax_uniform_pm1(k0, k1, (uint32_t)(b * G1SZ + cnode));
    m[(size_t)b * NN + IMG_N + cnode] = gibbs_decide(acc, H[IMG_N + cnode], u);
}

extern "C" void kernel_launch(void* const* d_in, const int* in_sizes, int n_in,
                              void* d_out, int out_size, void* d_ws, size_t ws_size,
                              hipStream_t stream) {
    const float* m_in = (const float*)d_in[0];
    const float* J    = (const float*)d_in[1];
    const float* H    = (const float*)d_in[2];
    float* m = (float*)d_out;

    hipMemcpyAsync(m, m_in, sizeof(float) * (size_t)BATCH * NN,
                   hipMemcpyDeviceToDevice, stream);

    // PARTITIONABLE key chain:
    // keys = split(key(1), 4) foldlike: keys[i] = threefry((0,1), (0, i))
    uint32_t K[4][2];
    for (int i = 0; i < 4; ++i)
        tf2x32(0u, 1u, 0u, (uint32_t)i, K[i][0], K[i][1]);

    for (int s = 0; s < 4; ++s) {  // sample_num = 4
        // k0, k1 = split(keys[s]) foldlike: k_j = threefry(keys[s], (0, j))
        uint32_t k0a, k0b, k1a, k1b;
        tf2x32(K[s][0], K[s][1], 0u, 0u, k0a, k0b);
        tf2x32(K[s][0], K[s][1], 0u, 1u, k1a, k1b);
        g0_kernel<<<1200, 256, 0, stream>>>(m, J, H, k0a, k0b);
        g1_kernel<<<1152, 256, 0, stream>>>(m, J, H, k1a, k1b);
    }
}